// Round 14
// baseline (249.179 us; speedup 1.0000x reference)
//
#include <hip/hip_runtime.h>
#include <hip/hip_bf16.h>

#define B_ 4
#define T_ 2048
#define C_ 1024
#define H_ 16
#define D_ 64
#define N3_ 3072
#define M_ (B_*T_)

typedef __bf16 bf16x8 __attribute__((ext_vector_type(8)));
typedef float f32x4 __attribute__((ext_vector_type(4)));
typedef float f32x16 __attribute__((ext_vector_type(16)));

__device__ __forceinline__ unsigned short f2bf(float f){
  __bf16 h = (__bf16)f;              // RNE fptrunc -> v_cvt on gfx950
  return __builtin_bit_cast(unsigned short, h);
}
__device__ __forceinline__ unsigned int pk2(float a, float b){
  return (unsigned int)f2bf(a) | ((unsigned int)f2bf(b)<<16);
}
// async global->LDS, 16B per lane; LDS dest = base + lane*16 (wave-uniform base)
__device__ __forceinline__ void gload_lds16(const unsigned short* g, unsigned short* l){
  __builtin_amdgcn_global_load_lds(
      (const __attribute__((address_space(1))) void*)g,
      (__attribute__((address_space(3))) void*)l, 16, 0, 0);
}

// ---------------- fused prep: x cvt + both weight transposes ----------------
// VERIFIED r10: 6 -> 4 dispatches = -10.3us (per-gap ~5us).
__device__ __forceinline__ void tr_tile(
    const float* __restrict__ src, unsigned short* __restrict__ dst,
    int K, int N, int bx, int by, float tile[32][33])
{
  const int tx = threadIdx.x & 31, ty = threadIdx.x >> 5; // 32 x 8
  const int nt = bx * 32, kt = by * 32;
  #pragma unroll
  for (int i=0;i<32;i+=8) tile[ty+i][tx] = src[(size_t)(kt+ty+i)*N + nt+tx];
  __syncthreads();
  #pragma unroll
  for (int i=0;i<32;i+=8) dst[(size_t)(nt+ty+i)*K + kt+tx] = f2bf(tile[tx][ty+i]);
}

#define XCVT_BLKS (M_*C_/2048)          // 4096
#define TRA_BLKS  ((N3_/32)*(C_/32))    // 3072
#define TRP_BLKS  ((C_/32)*(C_/32))     // 1024

__global__ __launch_bounds__(256) void prep(
    const float* __restrict__ X,  unsigned short* __restrict__ Xb,
    const float* __restrict__ Wa, unsigned short* __restrict__ Wat,
    const float* __restrict__ Wp, unsigned short* __restrict__ Wpt)
{
  __shared__ float tile[32][33];
  const int bid = (int)blockIdx.x;
  if (bid < XCVT_BLKS){
    const size_t i = ((size_t)bid*256 + threadIdx.x)*8;
    float4 f0 = *(const float4*)(X+i);
    float4 f1 = *(const float4*)(X+i+4);
    uint4 w = make_uint4(pk2(f0.x,f0.y), pk2(f0.z,f0.w), pk2(f1.x,f1.y), pk2(f1.z,f1.w));
    *(uint4*)(Xb+i) = w;
  } else if (bid < XCVT_BLKS + TRA_BLKS){
    const int t = bid - XCVT_BLKS;
    tr_tile(Wa, Wat, C_, N3_, t % (N3_/32), t / (N3_/32), tile);
  } else {
    const int t = bid - (XCVT_BLKS + TRA_BLKS);
    tr_tile(Wp, Wpt, C_, C_, t % (C_/32), t / (C_/32), tile);
  }
}

// ---------------- QKV GEMM: 512-thread / 8-wave 128x128 tile, BK=32 ---------
// r13: BK=64 was NULL (m233 predicted: barrier-halving alone doesn't help;
// occupancy dropped 28->19%). Fix the occupancy axis instead: 8 waves/block,
// per-wave 64x32 output, LDS 16KB, launch_bounds(512,4) caps VGPR at 128 ->
// 2 blocks/CU = 16 waves/CU of implicit drain-hiding overlap (m114).
// Staging: wave wid stages 16 rows of A and B; per-lane formula and swizzle
// identical to the r10-verified BK=32 code (key congruence traced r13).
// T1 (m192): XCD-chunked swizzle on flat grid 1536 (1536%8==0 -> bijective).
__global__ __launch_bounds__(512, 4) void qkv_gemm(
    const unsigned short* __restrict__ Xb, const unsigned short* __restrict__ Wt,
    const float* __restrict__ bias,
    unsigned short* __restrict__ Qb, unsigned short* __restrict__ Kb,
    unsigned short* __restrict__ Vt)
{
  __shared__ __align__(16) unsigned short As[128][32];
  __shared__ __align__(16) unsigned short Bs[128][32];
  const int tid = threadIdx.x;
  const int nbx = N3_/128;                       // 24
  const int cpx = (nbx*(M_/128))/8;              // 192 tiles per XCD
  const int id0 = (int)blockIdx.x;
  const int swz = (id0 & 7)*cpx + (id0 >> 3);
  const int m0 = (swz / nbx)*128, n0 = (swz % nbx)*128;
  const int wid = tid>>6, lane = tid&63, lm = lane&15, lq = lane>>4;
  const int wm = wid>>2, wn = wid&3;             // 2M x 4N waves
  f32x4 acc[4][2] = {};
  const int schunk = (lane&3) ^ ((lane>>3)&3);
  const unsigned short* gA = Xb + (size_t)(m0 + wid*16 + (lane>>2))*C_ + schunk*8;
  const unsigned short* gB = Wt + (size_t)(n0 + wid*16 + (lane>>2))*C_ + schunk*8;
  unsigned short* lA = &As[wid*16][0];
  unsigned short* lB = &Bs[wid*16][0];
  const int rkey = (lm>>1)&3;
  for (int k0=0;k0<C_;k0+=32){
    __syncthreads();
    gload_lds16(gA + k0, lA);
    gload_lds16(gB + k0, lB);
    __syncthreads();
    bf16x8 a[4], b[2];
    #pragma unroll
    for (int mt=0;mt<4;mt++) a[mt] = *(const bf16x8*)&As[wm*64+mt*16+lm][(lq^rkey)*8];
    #pragma unroll
    for (int nt=0;nt<2;nt++) b[nt] = *(const bf16x8*)&Bs[wn*32+nt*16+lm][(lq^rkey)*8];
    #pragma unroll
    for (int mt=0;mt<4;mt++)
      #pragma unroll
      for (int nt=0;nt<2;nt++)
        acc[mt][nt] = __builtin_amdgcn_mfma_f32_16x16x32_bf16(a[mt], b[nt], acc[mt][nt], 0,0,0);
  }
  const int sel = n0>>10;  // block-uniform: 0=Q,1=K,2=V
  const float qsc = (sel==0) ? 0.18033688f : 1.0f;  // 0.125*log2(e) folded into Q
  #pragma unroll
  for (int mt=0;mt<4;mt++){
    const int grow = m0 + wm*64 + mt*16 + lq*4;
    const int bb = grow>>11, tt0 = grow&2047;
    #pragma unroll
    for (int nt=0;nt<2;nt++){
      const int gcol = n0 + wn*32 + nt*16 + lm;
      const int hh = (gcol>>6)&15, dd = gcol&63;
      const float bv = bias[gcol];
      if (sel==2){
        ushort4 pv;
        pv.x = f2bf(acc[mt][nt][0] + bv);
        pv.y = f2bf(acc[mt][nt][1] + bv);
        pv.z = f2bf(acc[mt][nt][2] + bv);
        pv.w = f2bf(acc[mt][nt][3] + bv);
        *(ushort4*)&Vt[ ((size_t)(bb*H_+hh)*D_ + dd)*T_ + tt0 ] = pv;
      } else {
        unsigned short* dst = (sel==0) ? Qb : Kb;
        #pragma unroll
        for (int r=0;r<4;r++)
          dst[ ((size_t)(bb*H_+hh)*T_ + tt0 + r)*D_ + dd ] = f2bf((acc[mt][nt][r] + bv)*qsc);
      }
    }
  }
}

// ---------------- flash attention (32x32 swapped-QK^T, in-register P) -------
// VERIFIED r7: 82 -> ~69us vs 16x16 predecessor.
#define PV_CHUNK(SV, KG, C16) do{                                              \
  unsigned int X0_, X1_, Y0_, Y1_;                                             \
  asm("v_cvt_pk_bf16_f32 %0, %1, %2" : "=v"(X0_)                               \
      : "v"((float)(SV)[(C16)*8+0]), "v"((float)(SV)[(C16)*8+1]));             \
  asm("v_cvt_pk_bf16_f32 %0, %1, %2" : "=v"(X1_)                               \
      : "v"((float)(SV)[(C16)*8+2]), "v"((float)(SV)[(C16)*8+3]));             \
  asm("v_cvt_pk_bf16_f32 %0, %1, %2" : "=v"(Y0_)                               \
      : "v"((float)(SV)[(C16)*8+4]), "v"((float)(SV)[(C16)*8+5]));             \
  asm("v_cvt_pk_bf16_f32 %0, %1, %2" : "=v"(Y1_)                               \
      : "v"((float)(SV)[(C16)*8+6]), "v"((float)(SV)[(C16)*8+7]));             \
  asm volatile("v_permlane32_swap_b32 %0, %1" : "+v"(X0_), "+v"(Y0_));         \
  asm volatile("v_permlane32_swap_b32 %0, %1" : "+v"(X1_), "+v"(Y1_));         \
  uint4 pw_ = make_uint4(X0_, X1_, Y0_, Y1_);                                  \
  bf16x8 pf_ = __builtin_bit_cast(bf16x8, pw_);                                \
  const int ch_ = (((KG)*4 + (C16)*2 + hi) ^ l7)*8;                            \
  bf16x8 v0_ = *(const bf16x8*)&Vs[cb][l31][ch_];                              \
  bf16x8 v1_ = *(const bf16x8*)&Vs[cb][32+l31][ch_];                           \
  o0 = __builtin_amdgcn_mfma_f32_32x32x16_bf16(v0_, pf_, o0, 0,0,0);           \
  o1 = __builtin_amdgcn_mfma_f32_32x32x16_bf16(v1_, pf_, o1, 0,0,0);           \
}while(0)

__global__ __launch_bounds__(256, 3) void flash_attn(
    const unsigned short* __restrict__ Qb, const unsigned short* __restrict__ Kb,
    const unsigned short* __restrict__ Vt, unsigned short* __restrict__ Yb)
{
  __shared__ __align__(16) unsigned short Ks[2][64][64]; // swizzled chunks
  __shared__ __align__(16) unsigned short Vs[2][64][64]; // V^T, swizzled
  const int tid = threadIdx.x;
  const int wv = tid>>6, lane = tid&63;
  const int l31 = lane & 31, hi = lane >> 5, l7 = lane & 7;
  const int id = (int)blockIdx.x;
  const int bh = id & 63;                 // XCD L2 locality: same bh set per XCD
  const int qblk = 15 - (id >> 6);        // heavy q-blocks first
  const int qb = qblk*128;
  const int q0 = qb + wv*32;
  const unsigned short* Qh = Qb + (size_t)bh*T_*D_;
  const unsigned short* Kh = Kb + (size_t)bh*T_*D_;
  const unsigned short* Vh = Vt + (size_t)bh*D_*T_;
  // Q fragments (B-operand): lane holds Q[q0+l31][kc*16 + hi*8 + 0..7]
  bf16x8 aq[4];
  #pragma unroll
  for (int kc=0;kc<4;kc++)
    aq[kc] = *(const bf16x8*)&Qh[(size_t)(q0+l31)*D_ + kc*16 + hi*8];
  f32x16 o0 = {}, o1 = {};   // O^T: rows d (o0: 0-31, o1: 32-63), col q=l31
  float l_r = 0.f;
  // staging: wave wv covers rows [wv*16, wv*16+16)
  const int srl = lane>>3;
  const int sc  = (lane&7) ^ srl;
  const unsigned short* kg = Kh + (size_t)(wv*16 + srl)*D_ + sc*8;
  const unsigned short* vg = Vh + (size_t)(wv*16 + srl)*T_ + sc*8;
  {
    unsigned short* lk = &Ks[0][wv*16][0];
    unsigned short* lv = &Vs[0][wv*16][0];
    gload_lds16(kg,        lk);
    gload_lds16(kg + 8*D_, lk + 8*64);
    gload_lds16(vg,        lv);
    gload_lds16(vg + 8*T_, lv + 8*64);
  }
  const int JT = 2*qblk + 2;
  const int jmax = 2*qblk + (wv>>1);  // waves 0,1 finish one tile early
  for (int j=0;j<JT;j++){
    const int cb = j&1;
    __syncthreads();   // drains this wave's DMA (tile j) + prev-iter LDS reads
    if (j < JT-1){     // prefetch tile j+1 (hidden under compute)
      unsigned short* lk = &Ks[cb^1][wv*16][0];
      unsigned short* lv = &Vs[cb^1][wv*16][0];
      gload_lds16(kg + (size_t)((j+1)*64  )*D_, lk);
      gload_lds16(kg + (size_t)((j+1)*64+8)*D_, lk + 8*64);
      gload_lds16(vg + (j+1)*64,                lv);
      gload_lds16(vg + 8*T_ + (j+1)*64,         lv + 8*64);
    }
    if (j <= jmax){    // wave-uniform skip of fully-masked final tile
      // S^T = K Q^T : lane holds P[key = kg*32 + (r&3)+8*(r>>2)+4*hi][q = q0+l31]
      f32x16 s0 = {}, s1 = {};
      __builtin_amdgcn_s_setprio(1);
      #pragma unroll
      for (int kc=0;kc<4;kc++){
        const int ch = ((kc*2+hi) ^ l7)*8;
        bf16x8 k0 = *(const bf16x8*)&Ks[cb][l31][ch];
        bf16x8 k1 = *(const bf16x8*)&Ks[cb][32+l31][ch];
        s0 = __builtin_amdgcn_mfma_f32_32x32x16_bf16(k0, aq[kc], s0, 0,0,0);
        s1 = __builtin_amdgcn_mfma_f32_32x32x16_bf16(k1, aq[kc], s1, 0,0,0);
      }
      __builtin_amdgcn_s_setprio(0);
      // p = exp2(s) (Q pre-scaled); causal mask only on each wave's final tile
      if (j == jmax){
        const int qrel = ((wv&1)<<5) + l31;   // q - j*64, in-tile key limit
        #pragma unroll
        for (int r=0;r<16;r++){
          const int koff = (r&3) + 8*(r>>2) + 4*hi;
          s0[r] = (koff      <= qrel) ? exp2f(s0[r]) : 0.f;
          s1[r] = (32 + koff <= qrel) ? exp2f(s1[r]) : 0.f;
        }
      } else {
        #pragma unroll
        for (int r=0;r<16;r++){ s0[r] = exp2f(s0[r]); s1[r] = exp2f(s1[r]); }
      }
      #pragma unroll
      for (int r=0;r<16;r++) l_r += s0[r] + s1[r];
      // O^T += V^T P : P fragment built in-register (cvt_pk + permlane32_swap)
      __builtin_amdgcn_s_setprio(1);
      PV_CHUNK(s0, 0, 0); PV_CHUNK(s0, 0, 1);
      PV_CHUNK(s1, 1, 0); PV_CHUNK(s1, 1, 1);
      __builtin_amdgcn_s_setprio(0);
    }
  }
  // denominator: lane and lane^32 hold disjoint key sets for the same q
  float rs = l_r + __shfl_xor(l_r, 32);
  const float linv = 1.0f / rs;
  const int bb = bh>>4, hh = bh&15;
  const int q = q0 + l31;
  unsigned short* yrow = Yb + (size_t)(bb*T_ + q)*C_ + hh*64;
  #pragma unroll
  for (int g=0; g<4; g++){
    ushort4 y;
    y.x = f2bf(o0[4*g+0]*linv); y.y = f2bf(o0[4*g+1]*linv);
    y.z = f2bf(o0[4*g+2]*linv); y.w = f2bf(o0[4*g+3]*linv);
    *(ushort4*)&yrow[g*8 + hi*4] = y;
    ushort4 z;
    z.x = f2bf(o1[4*g+0]*linv); z.y = f2bf(o1[4*g+1]*linv);
    z.z = f2bf(o1[4*g+2]*linv); z.w = f2bf(o1[4*g+3]*linv);
    *(ushort4*)&yrow[32 + g*8 + hi*4] = z;
  }
}

// ---------------- proj GEMM: 512-thread / 8-wave 128x128 tile, BK=32 --------
// T1 swizzle: flat grid 512 (512%8==0 -> bijective chunked swizzle).
__global__ __launch_bounds__(512, 4) void proj_gemm(
    const unsigned short* __restrict__ Yb, const unsigned short* __restrict__ Wt,
    const float* __restrict__ bias, float* __restrict__ Out)
{
  __shared__ __align__(16) unsigned short As[128][32];
  __shared__ __align__(16) unsigned short Bs[128][32];
  const int tid = threadIdx.x;
  const int nbx = C_/128;                        // 8
  const int cpx = (nbx*(M_/128))/8;              // 64 tiles per XCD
  const int id0 = (int)blockIdx.x;
  const int swz = (id0 & 7)*cpx + (id0 >> 3);
  const int m0 = (swz / nbx)*128, n0 = (swz % nbx)*128;
  const int wid = tid>>6, lane = tid&63, lm = lane&15, lq = lane>>4;
  const int wm = wid>>2, wn = wid&3;
  f32x4 acc[4][2] = {};
  const int schunk = (lane&3) ^ ((lane>>3)&3);
  const unsigned short* gA = Yb + (size_t)(m0 + wid*16 + (lane>>2))*C_ + schunk*8;
  const unsigned short* gB = Wt + (size_t)(n0 + wid*16 + (lane>>2))*C_ + schunk*8;
  unsigned short* lA = &As[wid*16][0];
  unsigned short* lB = &Bs[wid*16][0];
  const int rkey = (lm>>1)&3;
  for (int k0=0;k0<C_;k0+=32){
    __syncthreads();
    gload_lds16(gA + k0, lA);
    gload_lds16(gB + k0, lB);
    __syncthreads();
    bf16x8 a[4], b[2];
    #pragma unroll
    for (int mt=0;mt<4;mt++) a[mt] = *(const bf16x8*)&As[wm*64+mt*16+lm][(lq^rkey)*8];
    #pragma unroll
    for (int nt=0;nt<2;nt++) b[nt] = *(const bf16x8*)&Bs[wn*32+nt*16+lm][(lq^rkey)*8];
    #pragma unroll
    for (int mt=0;mt<4;mt++)
      #pragma unroll
      for (int nt=0;nt<2;nt++)
        acc[mt][nt] = __builtin_amdgcn_mfma_f32_16x16x32_bf16(a[mt], b[nt], acc[mt][nt], 0,0,0);
  }
  #pragma unroll
  for (int mt=0;mt<4;mt++){
    const int grow = m0 + wm*64 + mt*16 + lq*4;
    #pragma unroll
    for (int nt=0;nt<2;nt++){
      const int gcol = n0 + wn*32 + nt*16 + lm;
      const float bv = bias[gcol];
      #pragma unroll
      for (int r=0;r<4;r++)
        Out[(size_t)(grow+r)*C_ + gcol] = acc[mt][nt][r] + bv;
    }
  }
}

extern "C" void kernel_launch(void* const* d_in, const int* in_sizes, int n_in,
                              void* d_out, int out_size, void* d_ws, size_t ws_size,
                              hipStream_t stream)
{
  const float* x      = (const float*)d_in[0];
  const float* W_attn = (const float*)d_in[1];
  const float* b_attn = (const float*)d_in[2];
  const float* W_proj = (const float*)d_in[3];
  const float* b_proj = (const float*)d_in[4];
  float* out = (float*)d_out;

  unsigned short* Wat = (unsigned short*)d_ws;            // [3072][1024] bf16
  unsigned short* Wpt = Wat + (size_t)N3_*C_;             // [1024][1024] bf16
  unsigned short* Xb  = Wpt + (size_t)C_*C_;              // [M,1024]  bf16
  unsigned short* Qb  = Xb  + (size_t)M_*C_;              // [B,H,T,D] bf16 (pre-scaled)
  unsigned short* Kb  = Qb  + (size_t)M_*C_;              // [B,H,T,D] bf16
  unsigned short* Vt  = Kb  + (size_t)M_*C_;              // [B,H,D,T] bf16
  unsigned short* Yb  = Vt  + (size_t)M_*C_;              // [M,1024]  bf16
  (void)ws_size; (void)in_sizes; (void)n_in; (void)out_size;

  prep      <<<dim3(XCVT_BLKS+TRA_BLKS+TRP_BLKS), 256, 0, stream>>>(
                x, Xb, W_attn, Wat, W_proj, Wpt);
  qkv_gemm  <<<dim3((N3_/128)*(M_/128)), 512, 0, stream>>>(Xb, Wat, b_attn, Qb, Kb, Vt);
  flash_attn<<<dim3(1024),               256, 0, stream>>>(Qb, Kb, Vt, Yb);
  proj_gemm <<<dim3((C_/128)*(M_/128)),  512, 0, stream>>>(Yb, Wpt, b_proj, out);
}